// Round 1
// baseline (244.916 us; speedup 1.0000x reference)
//
#include <hip/hip_runtime.h>
#include <stdint.h>

#define HD   1024
#define LD   4096
#define BATCH 4
#define KLEN 8192           // 2*L
#define LAM  0.1f
#define TAP_CAP 65536

typedef __attribute__((ext_vector_type(8))) short short8x;
typedef __attribute__((ext_vector_type(4))) float float4x;

struct Tap { int hd; float v; };

__device__ inline unsigned short f2bf(float x) {
    union { float f; uint32_t u; } v; v.f = x;
    uint32_t u = v.u;
    u += 0x7fffu + ((u >> 16) & 1u);
    return (unsigned short)(u >> 16);
}

__device__ inline void gload16(const void* g, void* l) {
    __builtin_amdgcn_global_load_lds(
        (const __attribute__((address_space(1))) void*)g,
        (__attribute__((address_space(3))) void*)l,
        16, 0, 0);
}

__device__ inline float silu_f(float x) { return x / (1.0f + __expf(-x)); }

// ---------------- zero the tap counter (ws is poisoned 0xAA each call) ------
__global__ void k_zero(int* p) {
    if (threadIdx.x < 16) p[threadIdx.x] = 0;
}

// ---------------- soft-threshold scan of the conv kernel --------------------
__global__ void k_scan(const float* __restrict__ kern, int* __restrict__ ntaps,
                       Tap* __restrict__ taps) {
    const float4* k4 = (const float4*)kern;
    int64_t total4 = (int64_t)HD * KLEN / 4;   // 2,097,152
    int64_t stride = (int64_t)gridDim.x * blockDim.x;
    for (int64_t i = blockIdx.x * blockDim.x + threadIdx.x; i < total4; i += stride) {
        float4 v = k4[i];
        float vals[4] = {v.x, v.y, v.z, v.w};
#pragma unroll
        for (int j = 0; j < 4; j++) {
            float a = fabsf(vals[j]) - LAM;
            if (a > 0.0f) {
                int e = (int)(i * 4 + j);
                int slot = atomicAdd(ntaps, 1);
                if (slot < TAP_CAP) { taps[slot].hd = e; taps[slot].v = copysignf(a, vals[j]); }
            }
        }
    }
}

// ---------------- general sparse conv (no-op when ntaps==0) -----------------
__global__ void k_conv(const float* __restrict__ u, const float* __restrict__ Dv,
                       const int* __restrict__ ntaps_p, const Tap* __restrict__ taps,
                       float* __restrict__ yfull) {
    int nt = *ntaps_p;
    if (nt == 0) return;
    nt = min(nt, TAP_CAP);
    int64_t total = (int64_t)BATCH * HD * LD;
    int64_t stride = (int64_t)gridDim.x * blockDim.x;
    for (int64_t i = (int64_t)blockIdx.x * blockDim.x + threadIdx.x; i < total; i += stride) {
        int t = (int)(i & (LD - 1));
        int64_t bh = i >> 12;
        int h = (int)(bh & (HD - 1));
        float acc = u[i] * Dv[h];
        for (int j = 0; j < nt; j++) {
            int hd = taps[j].hd;
            if ((hd >> 13) != h) continue;
            int d = hd & (KLEN - 1);
            int s;
            if (d <= t) s = t - d;
            else { s = t - d + KLEN; if (s >= LD) continue; }
            acc += taps[j].v * u[(bh << 12) + s];
        }
        yfull[i] = acc;
    }
}

// ---------------- W fp32 -> bf16 --------------------------------------------
__global__ void k_wconv(const float* __restrict__ W, unsigned short* __restrict__ Wbf) {
    int i = blockIdx.x * 256 + threadIdx.x;       // each thread: 8 elements
    const float4* w4 = (const float4*)W;
    float4 a = w4[i * 2], b = w4[i * 2 + 1];
    short8x o;
    o[0] = (short)f2bf(a.x); o[1] = (short)f2bf(a.y);
    o[2] = (short)f2bf(a.z); o[3] = (short)f2bf(a.w);
    o[4] = (short)f2bf(b.x); o[5] = (short)f2bf(b.y);
    o[6] = (short)f2bf(b.z); o[7] = (short)f2bf(b.w);
    *(short8x*)(Wbf + (int64_t)i * 8) = o;
}

// ---------------- V^T build: silu(u*D [+conv]) transposed to (B*L, H) bf16 --
__global__ __launch_bounds__(256) void k_vt(const float* __restrict__ u,
                                            const float* __restrict__ Dv,
                                            const float* __restrict__ yfull,
                                            const int* __restrict__ ntaps_p,
                                            unsigned short* __restrict__ Vt) {
    __shared__ float T[64][68];                  // [h][l], padded
    int nt = *ntaps_p;
    int lt = blockIdx.x * 64;
    int ht = blockIdx.y * 64;
    int b  = blockIdx.z;
    int tid = threadIdx.x;
    int lq = tid & 15;                           // l4 = lq*4
    int hh = tid >> 4;                           // 0..15
#pragma unroll
    for (int r = 0; r < 4; r++) {
        int h = hh + r * 16;
        int hg = ht + h;
        int64_t base = ((int64_t)b * HD + hg) * LD + lt + lq * 4;
        float4 v;
        if (nt == 0) {
            v = *(const float4*)(u + base);
            float d = Dv[hg];
            v.x *= d; v.y *= d; v.z *= d; v.w *= d;
        } else {
            v = *(const float4*)(yfull + base);
        }
        v.x = silu_f(v.x); v.y = silu_f(v.y); v.z = silu_f(v.z); v.w = silu_f(v.w);
        *(float4*)&T[h][lq * 4] = v;
    }
    __syncthreads();
    int l  = tid & 63;
    int hc = tid >> 6;                           // 0..3
#pragma unroll
    for (int oc = 0; oc < 2; oc++) {
        int h8 = (hc + oc * 4) * 8;              // 0..56 step 8
        short8x o;
#pragma unroll
        for (int j = 0; j < 8; j++) o[j] = (short)f2bf(T[h8 + j][l]);
        int64_t n = (int64_t)b * LD + lt + l;
        *(short8x*)(Vt + n * HD + ht + h8) = o;
    }
}

// ---------------- GEMM + GLU epilogue ---------------------------------------
// Z = Wbf(2048x1024) * Vt^T(1024x16384); out[b,h,l] = (z_a+b_a)*sigmoid(z_g+b_g)
// block: 128 a-rows + paired 128 g-rows x 128 cols, BK=32, 4 waves (2m x 2n)
__global__ __launch_bounds__(256, 2) void k_gemm(const unsigned short* __restrict__ Wbf,
                                                 const unsigned short* __restrict__ Vt,
                                                 const float* __restrict__ bvec,
                                                 float* __restrict__ out) {
    __shared__ unsigned short smem[12288];       // A: [0,8192) shorts (256 rows x 32), B: [8192,12288)
    int m0 = blockIdx.x * 128;                   // 0..896
    int n0 = blockIdx.y * 128;                   // 0..16256
    int tid = threadIdx.x;

    // staging: 1536 chunks of 16B, 6 per thread, LDS dest = chunk*16B (lane-contiguous)
    const unsigned short* gsrc[6];
    unsigned short* ldst[6];
#pragma unroll
    for (int i = 0; i < 6; i++) {
        int c = tid + i * 256;
        ldst[i] = smem + c * 8;
        if (c < 1024) {
            int r = c >> 2, kc = c & 3;
            int grow = (r < 128) ? (m0 + r) : (1024 + m0 + (r - 128));
            gsrc[i] = Wbf + (int64_t)grow * HD + kc * 8;
        } else {
            int cc = c - 1024;
            int col = cc >> 2, kc = cc & 3;
            gsrc[i] = Vt + (int64_t)(n0 + col) * HD + kc * 8;
        }
    }

    int lane = tid & 63;
    int wid  = tid >> 6;
    int wm = wid >> 1, wn = wid & 1;
    int l15 = lane & 15, quad = lane >> 4;

    int aoff[4], goff[4], boff[4];
#pragma unroll
    for (int i = 0; i < 4; i++) {
        int ra = wm * 64 + i * 16 + l15;
        aoff[i] = ra * 32 + quad * 8;
        goff[i] = (128 + ra) * 32 + quad * 8;
        int cb = wn * 64 + i * 16 + l15;
        boff[i] = 8192 + cb * 32 + quad * 8;
    }

    float4x acca[4][4], accg[4][4];
#pragma unroll
    for (int i = 0; i < 4; i++)
#pragma unroll
        for (int j = 0; j < 4; j++) {
            acca[i][j] = (float4x){0.f, 0.f, 0.f, 0.f};
            accg[i][j] = (float4x){0.f, 0.f, 0.f, 0.f};
        }

    for (int kt = 0; kt < 32; kt++) {
#pragma unroll
        for (int i = 0; i < 6; i++) gload16(gsrc[i], ldst[i]);
#pragma unroll
        for (int i = 0; i < 6; i++) gsrc[i] += 32;     // advance K by 32 bf16 (64B)
        __syncthreads();
        short8x af[4], gf[4], bf[4];
#pragma unroll
        for (int i = 0; i < 4; i++) {
            af[i] = *(const short8x*)(smem + aoff[i]);
            gf[i] = *(const short8x*)(smem + goff[i]);
            bf[i] = *(const short8x*)(smem + boff[i]);
        }
#pragma unroll
        for (int i = 0; i < 4; i++)
#pragma unroll
            for (int j = 0; j < 4; j++) {
                acca[i][j] = __builtin_amdgcn_mfma_f32_16x16x32_bf16(af[i], bf[j], acca[i][j], 0, 0, 0);
                accg[i][j] = __builtin_amdgcn_mfma_f32_16x16x32_bf16(gf[i], bf[j], accg[i][j], 0, 0, 0);
            }
        __syncthreads();
    }

    // epilogue: out[b,h,l] = (a + b_a) * sigmoid(g + b_g)
    int b = n0 >> 12;
#pragma unroll
    for (int i = 0; i < 4; i++) {
        int h = m0 + wm * 64 + i * 16 + quad * 4;
#pragma unroll
        for (int j = 0; j < 4; j++) {
            int n = n0 + wn * 64 + j * 16 + l15;
            int l = n & (LD - 1);
            float* op = out + ((int64_t)b * HD + h) * LD + l;
#pragma unroll
            for (int r = 0; r < 4; r++) {
                float av = acca[i][j][r] + bvec[h + r];
                float gv = accg[i][j][r] + bvec[1024 + h + r];
                op[(int64_t)r * LD] = av / (1.0f + __expf(-gv));
            }
        }
    }
}

extern "C" void kernel_launch(void* const* d_in, const int* in_sizes, int n_in,
                              void* d_out, int out_size, void* d_ws, size_t ws_size,
                              hipStream_t stream) {
    const float* u    = (const float*)d_in[0];   // (4,1024,4096)
    const float* kern = (const float*)d_in[1];   // (1,1024,8192)
    const float* Dv   = (const float*)d_in[2];   // (1,1024)
    const float* W    = (const float*)d_in[3];   // (2048,1024)
    const float* bv   = (const float*)d_in[4];   // (2048,)
    float* out = (float*)d_out;                  // (4,1024,4096)

    char* ws = (char*)d_ws;
    int* ntaps = (int*)ws;                                   // [0,64)
    Tap* taps  = (Tap*)(ws + 256);                           // 512 KiB cap
    unsigned short* Wbf = (unsigned short*)(ws + (1 << 20)); // 4 MiB
    unsigned short* Vt  = (unsigned short*)(ws + (8 << 20)); // 32 MiB
    float* yfull = (float*)(ws + (40 << 20));                // only touched if taps exist

    hipLaunchKernelGGL(k_zero,  dim3(1),          dim3(64),  0, stream, ntaps);
    hipLaunchKernelGGL(k_scan,  dim3(2048),       dim3(256), 0, stream, kern, ntaps, taps);
    hipLaunchKernelGGL(k_conv,  dim3(1024),       dim3(256), 0, stream, u, Dv, ntaps, taps, yfull);
    hipLaunchKernelGGL(k_wconv, dim3(1024),       dim3(256), 0, stream, W, Wbf);
    hipLaunchKernelGGL(k_vt,    dim3(64, 16, 4),  dim3(256), 0, stream, u, Dv, yfull, ntaps, Vt);
    hipLaunchKernelGGL(k_gemm,  dim3(8, 128),     dim3(256), 0, stream, Wbf, Vt, bv, out);
}

// Round 2
// 233.807 us; speedup vs baseline: 1.0475x; 1.0475x over previous
//
#include <hip/hip_runtime.h>
#include <stdint.h>

#define HD   1024
#define LD   4096
#define BATCH 4
#define KLEN 8192           // 2*L
#define LAM  0.1f
#define TAP_CAP 65536

typedef __attribute__((ext_vector_type(8))) short short8x;
typedef __attribute__((ext_vector_type(4))) float float4x;

struct Tap { int hd; float v; };

__device__ inline unsigned short f2bf(float x) {
    union { float f; uint32_t u; } v; v.f = x;
    uint32_t u = v.u;
    u += 0x7fffu + ((u >> 16) & 1u);
    return (unsigned short)(u >> 16);
}

__device__ inline void gload16(const void* g, void* l) {
    __builtin_amdgcn_global_load_lds(
        (const __attribute__((address_space(1))) void*)g,
        (__attribute__((address_space(3))) void*)l,
        16, 0, 0);
}

__device__ inline float silu_f(float x) { return x / (1.0f + __expf(-x)); }

// ---------------- fused: W fp32->bf16 (blocks 0..1023) + kernel scan --------
__global__ void k_prep(const float* __restrict__ kern, int* __restrict__ ntaps,
                       Tap* __restrict__ taps,
                       const float* __restrict__ W, unsigned short* __restrict__ Wbf) {
    if (blockIdx.x < 1024) {
        // W conversion: 2048x1024 fp32 -> bf16, 8 elems/thread
        int i = blockIdx.x * 256 + threadIdx.x;
        const float4* w4 = (const float4*)W;
        float4 a = w4[i * 2], b = w4[i * 2 + 1];
        short8x o;
        o[0] = (short)f2bf(a.x); o[1] = (short)f2bf(a.y);
        o[2] = (short)f2bf(a.z); o[3] = (short)f2bf(a.w);
        o[4] = (short)f2bf(b.x); o[5] = (short)f2bf(b.y);
        o[6] = (short)f2bf(b.z); o[7] = (short)f2bf(b.w);
        *(short8x*)(Wbf + (int64_t)i * 8) = o;
        return;
    }
    // soft-threshold scan (taps expected: zero on this data, but stay general)
    int bid = blockIdx.x - 1024;
    const float4* k4 = (const float4*)kern;
    int64_t total4 = (int64_t)HD * KLEN / 4;   // 2,097,152
    int64_t stride = (int64_t)2048 * 256;
    for (int64_t i = (int64_t)bid * 256 + threadIdx.x; i < total4; i += stride) {
        float4 v = k4[i];
        float vals[4] = {v.x, v.y, v.z, v.w};
#pragma unroll
        for (int j = 0; j < 4; j++) {
            float a = fabsf(vals[j]) - LAM;
            if (a > 0.0f) {
                int e = (int)(i * 4 + j);
                int slot = atomicAdd(ntaps, 1);
                if (slot < TAP_CAP) { taps[slot].hd = e; taps[slot].v = copysignf(a, vals[j]); }
            }
        }
    }
}

// ---------------- general sparse conv (no-op when ntaps==0) -----------------
__global__ void k_conv(const float* __restrict__ u, const float* __restrict__ Dv,
                       const int* __restrict__ ntaps_p, const Tap* __restrict__ taps,
                       float* __restrict__ yfull) {
    int nt = *ntaps_p;
    if (nt == 0) return;
    nt = min(nt, TAP_CAP);
    int64_t total = (int64_t)BATCH * HD * LD;
    int64_t stride = (int64_t)gridDim.x * blockDim.x;
    for (int64_t i = (int64_t)blockIdx.x * blockDim.x + threadIdx.x; i < total; i += stride) {
        int t = (int)(i & (LD - 1));
        int64_t bh = i >> 12;
        int h = (int)(bh & (HD - 1));
        float acc = u[i] * Dv[h];
        for (int j = 0; j < nt; j++) {
            int hd = taps[j].hd;
            if ((hd >> 13) != h) continue;
            int d = hd & (KLEN - 1);
            int s;
            if (d <= t) s = t - d;
            else { s = t - d + KLEN; if (s >= LD) continue; }
            acc += taps[j].v * u[(bh << 12) + s];
        }
        yfull[i] = acc;
    }
}

// ---------------- V^T build: silu(u*D [+conv]) transposed to (B*L, H) bf16 --
// pitch-65 fp32 LDS tile: 2-way banks on both phases; Vt writes coalesce as
// 8 x 128B segments per wave (was 64 x 16B at 2KB stride).
__global__ __launch_bounds__(256) void k_vt(const float* __restrict__ u,
                                            const float* __restrict__ Dv,
                                            const float* __restrict__ yfull,
                                            const int* __restrict__ ntaps_p,
                                            unsigned short* __restrict__ Vt) {
    __shared__ float T[64 * 65];                 // index h*65 + l
    int nt = *ntaps_p;
    int lt = blockIdx.x * 64;
    int ht = blockIdx.y * 64;
    int b  = blockIdx.z;
    int tid = threadIdx.x;
    int lq = tid & 15;                           // l4 = lq*4
    int hh = tid >> 4;                           // 0..15
#pragma unroll
    for (int r = 0; r < 4; r++) {
        int h = hh + r * 16;
        int hg = ht + h;
        int64_t base = ((int64_t)b * HD + hg) * LD + lt + lq * 4;
        float4 v;
        if (nt == 0) {
            v = *(const float4*)(u + base);
            float d = Dv[hg];
            v.x *= d; v.y *= d; v.z *= d; v.w *= d;
        } else {
            v = *(const float4*)(yfull + base);
        }
        int p = h * 65 + lq * 4;
        T[p]     = silu_f(v.x);
        T[p + 1] = silu_f(v.y);
        T[p + 2] = silu_f(v.z);
        T[p + 3] = silu_f(v.w);
    }
    __syncthreads();
    int h8 = (tid & 7) * 8;                      // 0..56
    int nb = tid >> 3;                           // 0..31
#pragma unroll
    for (int p = 0; p < 2; p++) {
        int nl = nb + p * 32;
        short8x o;
#pragma unroll
        for (int j = 0; j < 8; j++) o[j] = (short)f2bf(T[(h8 + j) * 65 + nl]);
        int64_t n = (int64_t)b * LD + lt + nl;
        *(short8x*)(Vt + n * HD + ht + h8) = o;
    }
}

// ---------------- GEMM + GLU epilogue ---------------------------------------
// Z = Wbf(2048x1024) * Vt^T(1024x16384); out[b,h,l] = (z_a+b_a)*sigmoid(z_g+b_g)
// block: 128 a-rows + paired 128 g-rows x 128 cols, BK=32, 4 waves (2m x 2n)
// k-chunk XOR swizzle in LDS (8-way -> 4-way bank conflicts); XCD-swizzled grid.
__global__ __launch_bounds__(256, 2) void k_gemm(const unsigned short* __restrict__ Wbf,
                                                 const unsigned short* __restrict__ Vt,
                                                 const float* __restrict__ bvec,
                                                 float* __restrict__ out) {
    __shared__ unsigned short smem[12288];       // A: [0,8192) (256 rows x 32), B: [8192,12288)
    // XCD swizzle: 1024 blocks; same-n m-tiles land on one XCD (blockIdx%8).
    int f   = blockIdx.x;
    int xcd = f & 7;
    int s   = f >> 3;                            // 0..127
    int ngrp = xcd * 16 + (s & 15);              // 0..127
    int mgrp = s >> 4;                           // 0..7
    int m0 = mgrp * 128;
    int n0 = ngrp * 128;
    int tid = threadIdx.x;

    // staging: 1536 chunks of 16B, 6/thread; LDS dest = chunk*16B (lane-contig).
    // slot within row is XOR-swizzled vs global k-chunk: g = slot ^ (row&3).
    const unsigned short* gsrc[6];
    unsigned short* ldst[6];
#pragma unroll
    for (int i = 0; i < 6; i++) {
        int c = tid + i * 256;
        ldst[i] = smem + c * 8;
        if (c < 1024) {
            int r = c >> 2, slot = c & 3;
            int kg = slot ^ (r & 3);
            int grow = (r < 128) ? (m0 + r) : (1024 + m0 + (r - 128));
            gsrc[i] = Wbf + (int64_t)grow * HD + kg * 8;
        } else {
            int cc = c - 1024;
            int col = cc >> 2, slot = cc & 3;
            int kg = slot ^ (col & 3);
            gsrc[i] = Vt + (int64_t)(n0 + col) * HD + kg * 8;
        }
    }

    int lane = tid & 63;
    int wid  = tid >> 6;
    int wm = wid >> 1, wn = wid & 1;
    int l15 = lane & 15, quad = lane >> 4;
    int kq = quad ^ (l15 & 3);                   // swizzled slot for reads

    int aoff[4], goff[4], boff[4];
#pragma unroll
    for (int i = 0; i < 4; i++) {
        int ra = wm * 64 + i * 16 + l15;
        aoff[i] = ra * 32 + kq * 8;
        goff[i] = (128 + ra) * 32 + kq * 8;
        int cb = wn * 64 + i * 16 + l15;
        boff[i] = 8192 + cb * 32 + kq * 8;
    }

    float4x acca[4][4], accg[4][4];
#pragma unroll
    for (int i = 0; i < 4; i++)
#pragma unroll
        for (int j = 0; j < 4; j++) {
            acca[i][j] = (float4x){0.f, 0.f, 0.f, 0.f};
            accg[i][j] = (float4x){0.f, 0.f, 0.f, 0.f};
        }

    for (int kt = 0; kt < 32; kt++) {
#pragma unroll
        for (int i = 0; i < 6; i++) gload16(gsrc[i], ldst[i]);
#pragma unroll
        for (int i = 0; i < 6; i++) gsrc[i] += 32;     // advance K by 32 bf16
        __syncthreads();
        short8x af[4], gf[4], bf[4];
#pragma unroll
        for (int i = 0; i < 4; i++) {
            af[i] = *(const short8x*)(smem + aoff[i]);
            gf[i] = *(const short8x*)(smem + goff[i]);
            bf[i] = *(const short8x*)(smem + boff[i]);
        }
#pragma unroll
        for (int i = 0; i < 4; i++)
#pragma unroll
            for (int j = 0; j < 4; j++) {
                acca[i][j] = __builtin_amdgcn_mfma_f32_16x16x32_bf16(af[i], bf[j], acca[i][j], 0, 0, 0);
                accg[i][j] = __builtin_amdgcn_mfma_f32_16x16x32_bf16(gf[i], bf[j], accg[i][j], 0, 0, 0);
            }
        __syncthreads();
    }

    // epilogue: out[b,h,l] = (a + b_a) * sigmoid(g + b_g)
    int b = n0 >> 12;
#pragma unroll
    for (int i = 0; i < 4; i++) {
        int h = m0 + wm * 64 + i * 16 + quad * 4;
        float ba[4], bg[4];
#pragma unroll
        for (int r = 0; r < 4; r++) { ba[r] = bvec[h + r]; bg[r] = bvec[1024 + h + r]; }
#pragma unroll
        for (int j = 0; j < 4; j++) {
            int n = n0 + wn * 64 + j * 16 + l15;
            int l = n & (LD - 1);
            float* op = out + ((int64_t)b * HD + h) * LD + l;
#pragma unroll
            for (int r = 0; r < 4; r++) {
                float av = acca[i][j][r] + ba[r];
                float gv = accg[i][j][r] + bg[r];
                op[(int64_t)r * LD] = av / (1.0f + __expf(-gv));
            }
        }
    }
}

extern "C" void kernel_launch(void* const* d_in, const int* in_sizes, int n_in,
                              void* d_out, int out_size, void* d_ws, size_t ws_size,
                              hipStream_t stream) {
    const float* u    = (const float*)d_in[0];   // (4,1024,4096)
    const float* kern = (const float*)d_in[1];   // (1,1024,8192)
    const float* Dv   = (const float*)d_in[2];   // (1,1024)
    const float* W    = (const float*)d_in[3];   // (2048,1024)
    const float* bv   = (const float*)d_in[4];   // (2048,)
    float* out = (float*)d_out;                  // (4,1024,4096)

    char* ws = (char*)d_ws;
    int* ntaps = (int*)ws;                                   // [0,256)
    Tap* taps  = (Tap*)(ws + 256);                           // 512 KiB cap
    unsigned short* Wbf = (unsigned short*)(ws + (1 << 20)); // 4 MiB
    unsigned short* Vt  = (unsigned short*)(ws + (8 << 20)); // 32 MiB
    float* yfull = (float*)(ws + (40 << 20));                // only touched if taps exist

    hipMemsetAsync(ntaps, 0, 256, stream);
    hipLaunchKernelGGL(k_prep, dim3(3072),      dim3(256), 0, stream, kern, ntaps, taps, W, (unsigned short*)Wbf);
    hipLaunchKernelGGL(k_conv, dim3(512),       dim3(256), 0, stream, u, Dv, ntaps, taps, yfull);
    hipLaunchKernelGGL(k_vt,   dim3(64, 16, 4), dim3(256), 0, stream, u, Dv, yfull, ntaps, Vt);
    hipLaunchKernelGGL(k_gemm, dim3(1024),      dim3(256), 0, stream, Wbf, Vt, bv, out);
}